// Round 1
// baseline (385.437 us; speedup 1.0000x reference)
//
#include <hip/hip_runtime.h>
#include <math.h>

#define NN 10000
#define NE 160000
#define NBATCH 8
#define TT 12
#define HPDIM 64
#define HVDIM 32

__device__ __forceinline__ void load_row12(const float* __restrict__ p, float* row) {
  const float4* p4 = reinterpret_cast<const float4*>(p);
  float4 r0 = p4[0], r1 = p4[1], r2 = p4[2];
  row[0]=r0.x; row[1]=r0.y; row[2]=r0.z; row[3]=r0.w;
  row[4]=r1.x; row[5]=r1.y; row[6]=r1.z; row[7]=r1.w;
  row[8]=r2.x; row[9]=r2.y; row[10]=r2.z; row[11]=r2.w;
}

// ---------------- node embeddings z[n*B+b][64] = feature @ fc_w^T ----------------
__global__ __launch_bounds__(256) void k_z(const float* __restrict__ feature,
                                           const float* __restrict__ fc_w,
                                           float* __restrict__ z) {
  __shared__ float w[HPDIM * TT];
  for (int i = threadIdx.x; i < HPDIM * TT; i += 256) w[i] = fc_w[i];
  __syncthreads();
  int t = blockIdx.x * 256 + threadIdx.x;
  if (t >= NN * NBATCH) return;
  float row[TT];
  load_row12(feature + (size_t)t * TT, row);
  float4* zr = reinterpret_cast<float4*>(z + (size_t)t * HPDIM);
#pragma unroll
  for (int h4 = 0; h4 < HPDIM / 4; ++h4) {
    float acc[4];
#pragma unroll
    for (int q = 0; q < 4; ++q) {
      float a = 0.f;
#pragma unroll
      for (int k = 0; k < TT; ++k) a = fmaf(row[k], w[(h4 * 4 + q) * TT + k], a);
      acc[q] = a;
    }
    float4 o; o.x = acc[0]; o.y = acc[1]; o.z = acc[2]; o.w = acc[3];
    zr[h4] = o;
  }
}

// ---------------- wg[c] = attn_w[c]*ln2_g[c]; consts = {S_wg, S_wb} ----------------
__global__ void k_prep(const float* __restrict__ attn_w, const float* __restrict__ ln2_g,
                       const float* __restrict__ ln2_b, float* __restrict__ wg,
                       float* __restrict__ consts) {
  __shared__ float r1[256], r2[256];
  int c = threadIdx.x;
  float vg = 0.f, vb = 0.f;
  if (c < 2 * HPDIM + 1) {
    float aw = attn_w[c];
    vg = aw * ln2_g[c];
    vb = aw * ln2_b[c];
    wg[c] = vg;
  }
  r1[c] = vg; r2[c] = vb;
  __syncthreads();
  for (int off = 128; off > 0; off >>= 1) {
    if (c < off) { r1[c] += r1[c + off]; r2[c] += r2[c + off]; }
    __syncthreads();
  }
  if (c == 0) { consts[0] = r1[0]; consts[1] = r2[0]; }
}

// ---------------- one NAM branch: sigmoid(w2 . relu(LN(row@w^T + b))) ----------------
__device__ __forceinline__ float nam_branch(const float* row, const float* __restrict__ w,
                                            const float* __restrict__ bias,
                                            const float* __restrict__ g,
                                            const float* __restrict__ bb,
                                            const float* __restrict__ w2, float b2) {
  float h[HVDIM];
  float s1 = 0.f, s2 = 0.f;
#pragma unroll
  for (int j = 0; j < HVDIM; ++j) {
    float acc = bias[j];
#pragma unroll
    for (int k = 0; k < TT; ++k) acc = fmaf(row[k], w[j * TT + k], acc);
    h[j] = acc; s1 += acc; s2 += acc * acc;
  }
  float m = s1 * (1.f / HVDIM);
  float var = s2 * (1.f / HVDIM) - m * m;
  float inv = rsqrtf(var + 1e-5f);
  float acc = b2;
#pragma unroll
  for (int j = 0; j < HVDIM; ++j) {
    float y = fmaf((h[j] - m) * inv, g[j], bb[j]);
    acc = fmaf(fmaxf(y, 0.f), w2[j], acc);
  }
  return 1.f / (1.f + expf(-acc));
}

// ---------------- per-(edge,batch): velocity, diffusion sum, attention logit ----------------
__global__ __launch_bounds__(256) void k_edge1(
    const float* __restrict__ upstream, const float* __restrict__ downstream,
    const float* __restrict__ distance, const float* __restrict__ alpha,
    const int* __restrict__ src, const int* __restrict__ dst,
    const float* __restrict__ feature, const float* __restrict__ z,
    const float* __restrict__ l11_w, const float* __restrict__ l11_b,
    const float* __restrict__ ln11_g, const float* __restrict__ ln11_b,
    const float* __restrict__ l12_w, const float* __restrict__ l12_b,
    const float* __restrict__ l21_w, const float* __restrict__ l21_b,
    const float* __restrict__ ln21_g, const float* __restrict__ ln21_b,
    const float* __restrict__ l22_w, const float* __restrict__ l22_b,
    const float* __restrict__ l3_w, const float* __restrict__ l3_b,
    const float* __restrict__ wg, const float* __restrict__ consts,
    float* __restrict__ sArr, float* __restrict__ exArr, unsigned* __restrict__ amax) {
  __shared__ float sw11[HVDIM * TT], sw21[HVDIM * TT];
  __shared__ float sb11[HVDIM], sg11[HVDIM], sbb11[HVDIM], sw12[HVDIM];
  __shared__ float sb21[HVDIM], sg21[HVDIM], sbb21[HVDIM], sw22[HVDIM];
  __shared__ float swg[132];
  __shared__ float sc[8];
  int tid = threadIdx.x;
  for (int i = tid; i < HVDIM * TT; i += 256) { sw11[i] = l11_w[i]; sw21[i] = l21_w[i]; }
  if (tid < HVDIM) {
    sb11[tid] = l11_b[tid]; sg11[tid] = ln11_g[tid]; sbb11[tid] = ln11_b[tid]; sw12[tid] = l12_w[tid];
    sb21[tid] = l21_b[tid]; sg21[tid] = ln21_g[tid]; sbb21[tid] = ln21_b[tid]; sw22[tid] = l22_w[tid];
  }
  if (tid < 2 * HPDIM + 1) swg[tid] = wg[tid];
  if (tid == 0) {
    sc[0] = l12_b[0]; sc[1] = l22_b[0];
    sc[2] = l3_w[0]; sc[3] = l3_w[1]; sc[4] = l3_w[2]; sc[5] = l3_b[0];
    sc[6] = consts[0]; sc[7] = consts[1];
  }
  __syncthreads();

  int t = blockIdx.x * 256 + tid;
  int e = t >> 3, b = t & 7;
  int se = src[e], de = dst[e];

  float row[TT];
  // velocity model
  load_row12(upstream + (size_t)t * TT, row);
  float xu = nam_branch(row, sw11, sb11, sg11, sbb11, sw12, sc[0]);
  load_row12(downstream + (size_t)t * TT, row);
  float xd = nam_branch(row, sw21, sb21, sg21, sbb21, sw22, sc[1]);

  float al = alpha[e];
  float vp = sc[2] * xu + sc[3] * xd + sc[4] * al + sc[5];
  float v = fmaxf(vp, 0.f) + log1pf(expf(-fabsf(vp)));  // stable softplus
  v = fminf(v, 3.f);
  float Tt = distance[e] / (v + 1e-5f);
  float Ti = fminf(fmaxf(rintf(Tt * 0.1f), 0.f), (float)(TT - 1));
  int n = TT - (int)Ti;                    // 1..12
  float acl = fminf(fmaxf(al, 0.f), 1.f);
  float F = 1.f / (1.f + acl * Tt);
  float omF = 1.f - F;

  // diffusion-weighted feature[src] sum: F * sum_{k<n} (1-F)^(n-1-k) f[k]
  load_row12(feature + ((size_t)se * NBATCH + b) * TT, row);
  float pw = 1.f, s = 0.f;
#pragma unroll
  for (int k = TT - 1; k >= 0; --k) {
    if (k <= n - 1) { s = fmaf(pw, row[k], s); pw *= omF; }
  }
  s *= F;
  sArr[t] = s;

  // attention logit: single-pass LN+dot over zc = [z[src], z[dst], T]
  float s1 = 0.f, s2 = 0.f, sd = 0.f;
  const float4* zs = reinterpret_cast<const float4*>(z + ((size_t)se * NBATCH + b) * HPDIM);
  const float4* zd = reinterpret_cast<const float4*>(z + ((size_t)de * NBATCH + b) * HPDIM);
#pragma unroll
  for (int c = 0; c < HPDIM / 4; ++c) {
    float4 x = zs[c];
    s1 += x.x + x.y + x.z + x.w;
    s2 += x.x * x.x + x.y * x.y + x.z * x.z + x.w * x.w;
    sd += swg[4 * c] * x.x + swg[4 * c + 1] * x.y + swg[4 * c + 2] * x.z + swg[4 * c + 3] * x.w;
  }
#pragma unroll
  for (int c = 0; c < HPDIM / 4; ++c) {
    float4 x = zd[c];
    s1 += x.x + x.y + x.z + x.w;
    s2 += x.x * x.x + x.y * x.y + x.z * x.z + x.w * x.w;
    sd += swg[HPDIM + 4 * c] * x.x + swg[HPDIM + 4 * c + 1] * x.y + swg[HPDIM + 4 * c + 2] * x.z + swg[HPDIM + 4 * c + 3] * x.w;
  }
  s1 += Tt; s2 += Tt * Tt; sd += swg[2 * HPDIM] * Tt;

  const float D = (float)(2 * HPDIM + 1);
  float m = s1 * (1.f / D);
  float var = s2 * (1.f / D) - m * m;
  float inv = rsqrtf(var + 1e-5f);
  float a = inv * (sd - m * sc[6]) + sc[7];
  a = (a >= 0.f) ? a : 0.01f * a;          // leaky_relu 0.01
  exArr[t] = a;                            // store logit; overwritten with exp later

  // segment max over src via order-preserving uint encoding (0 == -inf)
  unsigned bits = __float_as_uint(a);
  unsigned key = (bits & 0x80000000u) ? ~bits : (bits | 0x80000000u);
  atomicMax(&amax[(size_t)se * NBATCH + b], key);
}

// ---------------- pass 2: ex = exp(a - amax[src]); den[src] += ex ----------------
__global__ __launch_bounds__(256) void k_edge2(const int* __restrict__ src,
                                               const unsigned* __restrict__ amax,
                                               float* __restrict__ exArr,
                                               float* __restrict__ den) {
  int t = blockIdx.x * 256 + threadIdx.x;
  int e = t >> 3, b = t & 7;
  int si = src[e] * NBATCH + b;
  unsigned key = amax[si];
  unsigned bits = (key & 0x80000000u) ? (key ^ 0x80000000u) : ~key;
  float mx = __uint_as_float(bits);
  float ex = expf(exArr[t] - mx);
  exArr[t] = ex;
  atomicAdd(&den[si], ex);
}

// ---------------- pass 3: pred[dst] += (ex/den[src]) * s ----------------
__global__ __launch_bounds__(256) void k_edge3(const int* __restrict__ src,
                                               const int* __restrict__ dst,
                                               const float* __restrict__ exArr,
                                               const float* __restrict__ den,
                                               const float* __restrict__ sArr,
                                               float* __restrict__ pred) {
  int t = blockIdx.x * 256 + threadIdx.x;
  int e = t >> 3, b = t & 7;
  float ecoef = exArr[t] / den[src[e] * NBATCH + b];
  atomicAdd(&pred[dst[e] * NBATCH + b], ecoef * sArr[t]);
}

extern "C" void kernel_launch(void* const* d_in, const int* in_sizes, int n_in,
                              void* d_out, int out_size, void* d_ws, size_t ws_size,
                              hipStream_t stream) {
  const float* feature   = (const float*)d_in[0];
  const float* upstream  = (const float*)d_in[1];
  const float* downstream= (const float*)d_in[2];
  const float* distance  = (const float*)d_in[3];
  const int*   src       = (const int*)d_in[4];
  const int*   dst       = (const int*)d_in[5];
  const float* alpha     = (const float*)d_in[6];
  const float* fc_w      = (const float*)d_in[7];
  const float* ln2_g     = (const float*)d_in[8];
  const float* ln2_b     = (const float*)d_in[9];
  const float* attn_w    = (const float*)d_in[10];
  const float* l11_w     = (const float*)d_in[11];
  const float* l11_b     = (const float*)d_in[12];
  const float* ln11_g    = (const float*)d_in[13];
  const float* ln11_b    = (const float*)d_in[14];
  const float* l12_w     = (const float*)d_in[15];
  const float* l12_b     = (const float*)d_in[16];
  const float* l21_w     = (const float*)d_in[17];
  const float* l21_b     = (const float*)d_in[18];
  const float* ln21_g    = (const float*)d_in[19];
  const float* ln21_b    = (const float*)d_in[20];
  const float* l22_w     = (const float*)d_in[21];
  const float* l22_b     = (const float*)d_in[22];
  const float* l3_w      = (const float*)d_in[23];
  const float* l3_b      = (const float*)d_in[24];
  float* pred = (float*)d_out;

  float* ws = (float*)d_ws;
  float* z      = ws;                                   // NN*NBATCH*HPDIM
  float* sArr   = z + (size_t)NN * NBATCH * HPDIM;      // NE*NBATCH
  float* exArr  = sArr + (size_t)NE * NBATCH;           // NE*NBATCH
  float* den    = exArr + (size_t)NE * NBATCH;          // NN*NBATCH
  unsigned* amax = (unsigned*)(den + (size_t)NN * NBATCH); // NN*NBATCH
  float* wg     = (float*)(amax + (size_t)NN * NBATCH); // 132
  float* consts = wg + 132;                             // 2

  hipMemsetAsync(pred, 0, (size_t)NN * NBATCH * sizeof(float), stream);
  hipMemsetAsync(den, 0, (size_t)NN * NBATCH * sizeof(float), stream);
  hipMemsetAsync(amax, 0, (size_t)NN * NBATCH * sizeof(unsigned), stream);

  k_z<<<(NN * NBATCH + 255) / 256, 256, 0, stream>>>(feature, fc_w, z);
  k_prep<<<1, 256, 0, stream>>>(attn_w, ln2_g, ln2_b, wg, consts);

  int eb = NE * NBATCH;
  k_edge1<<<eb / 256, 256, 0, stream>>>(upstream, downstream, distance, alpha, src, dst,
                                        feature, z,
                                        l11_w, l11_b, ln11_g, ln11_b, l12_w, l12_b,
                                        l21_w, l21_b, ln21_g, ln21_b, l22_w, l22_b,
                                        l3_w, l3_b, wg, consts, sArr, exArr, amax);
  k_edge2<<<eb / 256, 256, 0, stream>>>(src, amax, exArr, den);
  k_edge3<<<eb / 256, 256, 0, stream>>>(src, dst, exArr, den, sArr, pred);
}

// Round 2
// 244.213 us; speedup vs baseline: 1.5783x; 1.5783x over previous
//
#include <hip/hip_runtime.h>
#include <math.h>

#define NN 10000
#define NE 160000
#define NB 8
#define TT 12
#define HP 64
#define HV 32

__device__ __forceinline__ void load_row12(const float* __restrict__ p, float* row) {
  const float4* p4 = reinterpret_cast<const float4*>(p);
  float4 r0 = p4[0], r1 = p4[1], r2 = p4[2];
  row[0]=r0.x; row[1]=r0.y; row[2]=r0.z; row[3]=r0.w;
  row[4]=r1.x; row[5]=r1.y; row[6]=r1.z; row[7]=r1.w;
  row[8]=r2.x; row[9]=r2.y; row[10]=r2.z; row[11]=r2.w;
}

// dot of row[0..11] with weight row j of a [*,12] matrix, via uniform float4 loads
__device__ __forceinline__ float dot12(const float* row, const float4* __restrict__ w4, int j) {
  float4 a = w4[j*3+0], b = w4[j*3+1], c = w4[j*3+2];
  float acc = row[0]*a.x;
  acc = fmaf(row[1], a.y, acc);
  acc = fmaf(row[2], a.z, acc);
  acc = fmaf(row[3], a.w, acc);
  acc = fmaf(row[4], b.x, acc);
  acc = fmaf(row[5], b.y, acc);
  acc = fmaf(row[6], b.z, acc);
  acc = fmaf(row[7], b.w, acc);
  acc = fmaf(row[8], c.x, acc);
  acc = fmaf(row[9], c.y, acc);
  acc = fmaf(row[10], c.z, acc);
  acc = fmaf(row[11], c.w, acc);
  return acc;
}

// ---------------- consts: S_wg, S_wb, wgT (attention LN collapse constants) ----------------
__global__ void k_prep(const float* __restrict__ attn_w, const float* __restrict__ ln2_g,
                       const float* __restrict__ ln2_b, float* __restrict__ consts) {
  __shared__ float r1[256], r2[256];
  int c = threadIdx.x;
  float vg = 0.f, vb = 0.f;
  if (c < 2 * HP + 1) {
    float aw = attn_w[c];
    vg = aw * ln2_g[c];
    vb = aw * ln2_b[c];
  }
  r1[c] = vg; r2[c] = vb;
  __syncthreads();
  for (int off = 128; off > 0; off >>= 1) {
    if (c < off) { r1[c] += r1[c + off]; r2[c] += r2[c + off]; }
    __syncthreads();
  }
  if (c == 0) {
    consts[0] = r1[0];
    consts[1] = r2[0];
    consts[2] = attn_w[2 * HP] * ln2_g[2 * HP];
  }
}

// ---------------- per-(node,batch) attention aggregates: {A1, A2, Dsrc, Ddst} ----------------
__global__ __launch_bounds__(256) void k_node(const float* __restrict__ feature,
                                              const float* __restrict__ fc_w,
                                              const float* __restrict__ attn_w,
                                              const float* __restrict__ ln2_g,
                                              float4* __restrict__ nodeAgg) {
  int t = blockIdx.x * 256 + threadIdx.x;
  if (t >= NN * NB) return;
  float row[TT];
  load_row12(feature + (size_t)t * TT, row);
  const float4* w4 = reinterpret_cast<const float4*>(fc_w);
  float A1 = 0.f, A2 = 0.f, Ds = 0.f, Dd = 0.f;
#pragma unroll
  for (int c = 0; c < HP; ++c) {
    float z = dot12(row, w4, c);
    A1 += z;
    A2 = fmaf(z, z, A2);
    Ds = fmaf(attn_w[c] * ln2_g[c], z, Ds);
    Dd = fmaf(attn_w[HP + c] * ln2_g[HP + c], z, Dd);
  }
  float4 o; o.x = A1; o.y = A2; o.z = Ds; o.w = Dd;
  nodeAgg[t] = o;
}

// ---------------- one NAM branch: sigmoid(w2 . relu(LN(row@w^T + b))) ----------------
__device__ __forceinline__ float nam_branch(const float* row, const float* __restrict__ w,
                                            const float* __restrict__ bias,
                                            const float* __restrict__ g,
                                            const float* __restrict__ bb,
                                            const float* __restrict__ w2, float b2) {
  const float4* w4 = reinterpret_cast<const float4*>(w);
  float h[HV];
  float s1 = 0.f, s2 = 0.f;
#pragma unroll
  for (int j = 0; j < HV; ++j) {
    float acc = bias[j] + dot12(row, w4, j);
    h[j] = acc; s1 += acc; s2 = fmaf(acc, acc, s2);
  }
  float m = s1 * (1.f / HV);
  float var = s2 * (1.f / HV) - m * m;
  float inv = rsqrtf(var + 1e-5f);
  float acc = b2;
#pragma unroll
  for (int j = 0; j < HV; ++j) {
    float y = fmaf((h[j] - m) * inv, g[j], bb[j]);
    acc = fmaf(fmaxf(y, 0.f), w2[j], acc);
  }
  return 1.f / (1.f + __expf(-acc));
}

// ---------------- per-(edge,batch): velocity, diffusion sum, attention; prod = ex*s ----------------
__global__ __launch_bounds__(256) void k_edge1(
    const float* __restrict__ upstream, const float* __restrict__ downstream,
    const float* __restrict__ distance, const float* __restrict__ alpha,
    const int* __restrict__ src, const int* __restrict__ dst,
    const float* __restrict__ feature, const float4* __restrict__ nodeAgg,
    const float* __restrict__ l11_w, const float* __restrict__ l11_b,
    const float* __restrict__ ln11_g, const float* __restrict__ ln11_b,
    const float* __restrict__ l12_w, const float* __restrict__ l12_b,
    const float* __restrict__ l21_w, const float* __restrict__ l21_b,
    const float* __restrict__ ln21_g, const float* __restrict__ ln21_b,
    const float* __restrict__ l22_w, const float* __restrict__ l22_b,
    const float* __restrict__ l3_w, const float* __restrict__ l3_b,
    const float* __restrict__ consts,
    float* __restrict__ prod, float* __restrict__ den) {
  int t = blockIdx.x * 256 + threadIdx.x;
  int e = t >> 3, b = t & 7;
  int se = src[e], de = dst[e];

  float row[TT];
  load_row12(upstream + (size_t)t * TT, row);
  float xu = nam_branch(row, l11_w, l11_b, ln11_g, ln11_b, l12_w, l12_b[0]);
  load_row12(downstream + (size_t)t * TT, row);
  float xd = nam_branch(row, l21_w, l21_b, ln21_g, ln21_b, l22_w, l22_b[0]);

  float al = alpha[e];
  float vp = fmaf(l3_w[0], xu, fmaf(l3_w[1], xd, fmaf(l3_w[2], al, l3_b[0])));
  float v = fmaxf(vp, 0.f) + log1pf(__expf(-fabsf(vp)));  // stable softplus
  v = fminf(v, 3.f);
  float Tt = distance[e] / (v + 1e-5f);
  float Ti = fminf(fmaxf(rintf(Tt * 0.1f), 0.f), (float)(TT - 1));
  int n = TT - (int)Ti;  // 1..12
  float acl = fminf(fmaxf(al, 0.f), 1.f);
  float F = 1.f / (1.f + acl * Tt);
  float omF = 1.f - F;

  // diffusion-weighted feature[src] sum: F * sum_{k<n} (1-F)^(n-1-k) f[k]
  load_row12(feature + ((size_t)se * NB + b) * TT, row);
  float pw = 1.f, s = 0.f;
#pragma unroll
  for (int k = TT - 1; k >= 0; --k) {
    if (k <= n - 1) { s = fmaf(pw, row[k], s); pw *= omF; }
  }
  s *= F;

  // attention logit from node aggregates (single-pass collapsed LN+dot)
  float4 As = nodeAgg[(size_t)se * NB + b];
  float4 Ad = nodeAgg[(size_t)de * NB + b];
  float s1 = As.x + Ad.x + Tt;
  float s2 = As.y + Ad.y + Tt * Tt;
  float sd = As.z + Ad.w + consts[2] * Tt;

  float m = s1 * (1.f / 129.f);
  float var = s2 * (1.f / 129.f) - m * m;
  float inv = rsqrtf(var + 1e-5f);
  float a = fmaf(inv, sd - m * consts[0], consts[1]);
  a = (a >= 0.f) ? a : 0.01f * a;  // leaky_relu 0.01

  // no segment-max needed: |a| <= ~|wg|_2*sqrt(129) (Cauchy-Schwarz) << 80
  float ex = __expf(a);
  prod[t] = ex * s;
  atomicAdd(&den[(size_t)se * NB + b], ex);
}

// ---------------- scatter: pred[dst] += prod / den[src] ----------------
__global__ __launch_bounds__(256) void k_edge2(const int* __restrict__ src,
                                               const int* __restrict__ dst,
                                               const float* __restrict__ prod,
                                               const float* __restrict__ den,
                                               float* __restrict__ pred) {
  int t = blockIdx.x * 256 + threadIdx.x;
  int e = t >> 3, b = t & 7;
  float p = prod[t] / den[(size_t)src[e] * NB + b];
  atomicAdd(&pred[(size_t)dst[e] * NB + b], p);
}

extern "C" void kernel_launch(void* const* d_in, const int* in_sizes, int n_in,
                              void* d_out, int out_size, void* d_ws, size_t ws_size,
                              hipStream_t stream) {
  const float* feature   = (const float*)d_in[0];
  const float* upstream  = (const float*)d_in[1];
  const float* downstream= (const float*)d_in[2];
  const float* distance  = (const float*)d_in[3];
  const int*   src       = (const int*)d_in[4];
  const int*   dst       = (const int*)d_in[5];
  const float* alpha     = (const float*)d_in[6];
  const float* fc_w      = (const float*)d_in[7];
  const float* ln2_g     = (const float*)d_in[8];
  const float* ln2_b     = (const float*)d_in[9];
  const float* attn_w    = (const float*)d_in[10];
  const float* l11_w     = (const float*)d_in[11];
  const float* l11_b     = (const float*)d_in[12];
  const float* ln11_g    = (const float*)d_in[13];
  const float* ln11_b    = (const float*)d_in[14];
  const float* l12_w     = (const float*)d_in[15];
  const float* l12_b     = (const float*)d_in[16];
  const float* l21_w     = (const float*)d_in[17];
  const float* l21_b     = (const float*)d_in[18];
  const float* ln21_g    = (const float*)d_in[19];
  const float* ln21_b    = (const float*)d_in[20];
  const float* l22_w     = (const float*)d_in[21];
  const float* l22_b     = (const float*)d_in[22];
  const float* l3_w      = (const float*)d_in[23];
  const float* l3_b      = (const float*)d_in[24];
  float* pred = (float*)d_out;

  float* ws = (float*)d_ws;
  float4* nodeAgg = (float4*)ws;                                  // NN*NB float4
  float* prod   = ws + (size_t)NN * NB * 4;                       // NE*NB
  float* den    = prod + (size_t)NE * NB;                         // NN*NB
  float* consts = den + (size_t)NN * NB;                          // 3

  hipMemsetAsync(pred, 0, (size_t)NN * NB * sizeof(float), stream);
  hipMemsetAsync(den, 0, (size_t)NN * NB * sizeof(float), stream);

  k_prep<<<1, 256, 0, stream>>>(attn_w, ln2_g, ln2_b, consts);
  k_node<<<(NN * NB + 255) / 256, 256, 0, stream>>>(feature, fc_w, attn_w, ln2_g, nodeAgg);

  int eb = NE * NB;
  k_edge1<<<eb / 256, 256, 0, stream>>>(upstream, downstream, distance, alpha, src, dst,
                                        feature, nodeAgg,
                                        l11_w, l11_b, ln11_g, ln11_b, l12_w, l12_b,
                                        l21_w, l21_b, ln21_g, ln21_b, l22_w, l22_b,
                                        l3_w, l3_b, consts, prod, den);
  k_edge2<<<eb / 256, 256, 0, stream>>>(src, dst, prod, den, pred);
}

// Round 4
// 240.774 us; speedup vs baseline: 1.6008x; 1.0143x over previous
//
#include <hip/hip_runtime.h>
#include <math.h>

#define NN 10000
#define NE 160000
#define NB 8
#define TT 12
#define HP 64
#define HV 32

// workspace float layout: nodeAgg[NN*NB*4] | prod[NE*NB] | den[NN*NB] | consts[4]
#define WS_FLOATS (NN * NB * 4 + NE * NB + NN * NB + 4)
#define WS_F4 ((WS_FLOATS) / 4)   // 420001, exact

typedef float v2 __attribute__((ext_vector_type(2)));

__device__ __forceinline__ v2 fma2(v2 a, v2 b, v2 c) { return __builtin_elementwise_fma(a, b, c); }

__device__ __forceinline__ void load_row12v(const float* __restrict__ p, v2* r2) {
  const float4* p4 = reinterpret_cast<const float4*>(p);
  float4 a = p4[0], b = p4[1], c = p4[2];
  r2[0] = (v2){a.x, a.y}; r2[1] = (v2){a.z, a.w};
  r2[2] = (v2){b.x, b.y}; r2[3] = (v2){b.z, b.w};
  r2[4] = (v2){c.x, c.y}; r2[5] = (v2){c.z, c.w};
}

__device__ __forceinline__ void load_row12(const float* __restrict__ p, float* row) {
  const float4* p4 = reinterpret_cast<const float4*>(p);
  float4 r0 = p4[0], r1 = p4[1], r2 = p4[2];
  row[0]=r0.x; row[1]=r0.y; row[2]=r0.z; row[3]=r0.w;
  row[4]=r1.x; row[5]=r1.y; row[6]=r1.z; row[7]=r1.w;
  row[8]=r2.x; row[9]=r2.y; row[10]=r2.z; row[11]=r2.w;
}

// ---------------- zero EVERYTHING we read or accumulate into (pred + full ws span) ----------------
// Replaces hipMemsetAsync graph nodes; guarantees no read-before-write of poisoned memory.
__global__ __launch_bounds__(256) void k_init(float4* __restrict__ ws4, float4* __restrict__ pred4) {
  unsigned i = blockIdx.x * 256 + threadIdx.x;
  float4 z; z.x = 0.f; z.y = 0.f; z.z = 0.f; z.w = 0.f;
  for (unsigned j = i; j < (unsigned)WS_F4; j += 256u * 1024u) ws4[j] = z;
  if (i < NN * NB / 4) pred4[i] = z;
}

// ---------------- per-(node,batch) attention aggregates {A1,A2,Dsrc,Ddst}; block 0 also writes consts ----------------
__global__ __launch_bounds__(256) void k_node(const float* __restrict__ feature,
                                              const float* __restrict__ fc_w,
                                              const float* __restrict__ attn_w,
                                              const float* __restrict__ ln2_g,
                                              const float* __restrict__ ln2_b,
                                              float4* __restrict__ nodeAgg,
                                              float* __restrict__ consts) {
  if (blockIdx.x == 0) {
    __shared__ float r1[256], r2[256];
    int c = threadIdx.x;
    float vg = 0.f, vb = 0.f;
    if (c < 2 * HP + 1) {
      float aw = attn_w[c];
      vg = aw * ln2_g[c];
      vb = aw * ln2_b[c];
    }
    r1[c] = vg; r2[c] = vb;
    __syncthreads();
    for (int off = 128; off > 0; off >>= 1) {
      if (c < off) { r1[c] += r1[c + off]; r2[c] += r2[c + off]; }
      __syncthreads();
    }
    if (c == 0) {
      consts[0] = r1[0];                                // S_wg
      consts[1] = r2[0];                                // S_wb
      consts[2] = attn_w[2 * HP] * ln2_g[2 * HP];       // wg for the T column
      consts[3] = 0.f;
    }
  }

  int t = blockIdx.x * 256 + threadIdx.x;
  if (t >= NN * NB) return;
  v2 row2[6];
  load_row12v(feature + (size_t)t * TT, row2);
  const v2* wv  = reinterpret_cast<const v2*>(fc_w);    // [64][6]
  const v2* awv = reinterpret_cast<const v2*>(attn_w);
  const v2* gv  = reinterpret_cast<const v2*>(ln2_g);
  v2 A1p = {0.f,0.f}, A2p = {0.f,0.f}, Dsp = {0.f,0.f}, Ddp = {0.f,0.f};
#pragma unroll
  for (int c2 = 0; c2 < HP / 2; ++c2) {
    v2 a0 = {0.f,0.f}, a1 = {0.f,0.f};
#pragma unroll
    for (int k2 = 0; k2 < 6; ++k2) {
      a0 = fma2(row2[k2], wv[(2 * c2) * 6 + k2], a0);
      a1 = fma2(row2[k2], wv[(2 * c2 + 1) * 6 + k2], a1);
    }
    v2 zp = {a0.x + a0.y, a1.x + a1.y};
    A1p += zp;
    A2p = fma2(zp, zp, A2p);
    v2 wgs = awv[c2] * gv[c2];
    v2 wgd = awv[HP / 2 + c2] * gv[HP / 2 + c2];
    Dsp = fma2(wgs, zp, Dsp);
    Ddp = fma2(wgd, zp, Ddp);
  }
  float4 o;
  o.x = A1p.x + A1p.y; o.y = A2p.x + A2p.y; o.z = Dsp.x + Dsp.y; o.w = Ddp.x + Ddp.y;
  nodeAgg[t] = o;
}

// ---------------- one NAM branch (packed-fp32): sigmoid(w2 . relu(LN(row@w^T + b))) ----------------
__device__ __forceinline__ float nam_branch(const v2* row2, const float* __restrict__ w,
                                            const float* __restrict__ bias,
                                            const float* __restrict__ g,
                                            const float* __restrict__ bb,
                                            const float* __restrict__ w2, float b2) {
  const v2* wv    = reinterpret_cast<const v2*>(w);     // [32][6]
  const v2* biasv = reinterpret_cast<const v2*>(bias);
  const v2* gv    = reinterpret_cast<const v2*>(g);
  const v2* bbv   = reinterpret_cast<const v2*>(bb);
  const v2* w2v   = reinterpret_cast<const v2*>(w2);
  v2 hp[HV / 2];
  v2 sp1 = {0.f,0.f}, sp2 = {0.f,0.f};
#pragma unroll
  for (int j2 = 0; j2 < HV / 2; ++j2) {
    v2 a0 = {0.f,0.f}, a1 = {0.f,0.f};
#pragma unroll
    for (int k2 = 0; k2 < 6; ++k2) {
      a0 = fma2(row2[k2], wv[(2 * j2) * 6 + k2], a0);
      a1 = fma2(row2[k2], wv[(2 * j2 + 1) * 6 + k2], a1);
    }
    v2 bp = biasv[j2];
    v2 h = {a0.x + a0.y + bp.x, a1.x + a1.y + bp.y};
    hp[j2] = h;
    sp1 += h;
    sp2 = fma2(h, h, sp2);
  }
  float s1 = sp1.x + sp1.y, s2 = sp2.x + sp2.y;
  float m = s1 * (1.f / HV);
  float var = s2 * (1.f / HV) - m * m;
  float inv = rsqrtf(var + 1e-5f);
  v2 inv2 = {inv, inv};
  float nmi = -m * inv;
  v2 nmi2 = {nmi, nmi};
  v2 acc2 = {0.f,0.f};
  v2 zero = {0.f,0.f};
#pragma unroll
  for (int j2 = 0; j2 < HV / 2; ++j2) {
    v2 tt = fma2(hp[j2], inv2, nmi2);            // (h - m) * inv
    v2 y = fma2(tt, gv[j2], bbv[j2]);
    y = __builtin_elementwise_max(y, zero);
    acc2 = fma2(y, w2v[j2], acc2);
  }
  float acc = acc2.x + acc2.y + b2;
  return 1.f / (1.f + __expf(-acc));
}

// ---------------- per-(edge,batch): velocity, diffusion sum, attention; prod = ex*s ----------------
__global__ __launch_bounds__(256) void k_edge1(
    const float* __restrict__ upstream, const float* __restrict__ downstream,
    const float* __restrict__ distance, const float* __restrict__ alpha,
    const int* __restrict__ src, const int* __restrict__ dst,
    const float* __restrict__ feature, const float4* __restrict__ nodeAgg,
    const float* __restrict__ l11_w, const float* __restrict__ l11_b,
    const float* __restrict__ ln11_g, const float* __restrict__ ln11_b,
    const float* __restrict__ l12_w, const float* __restrict__ l12_b,
    const float* __restrict__ l21_w, const float* __restrict__ l21_b,
    const float* __restrict__ ln21_g, const float* __restrict__ ln21_b,
    const float* __restrict__ l22_w, const float* __restrict__ l22_b,
    const float* __restrict__ l3_w, const float* __restrict__ l3_b,
    const float* __restrict__ consts,
    float* __restrict__ prod, float* __restrict__ den) {
  int t = blockIdx.x * 256 + threadIdx.x;
  int e = t >> 3, b = t & 7;
  int se = src[e], de = dst[e];

  v2 row2[6];
  load_row12v(upstream + (size_t)t * TT, row2);
  float xu = nam_branch(row2, l11_w, l11_b, ln11_g, ln11_b, l12_w, l12_b[0]);
  load_row12v(downstream + (size_t)t * TT, row2);
  float xd = nam_branch(row2, l21_w, l21_b, ln21_g, ln21_b, l22_w, l22_b[0]);

  float al = alpha[e];
  float vp = fmaf(l3_w[0], xu, fmaf(l3_w[1], xd, fmaf(l3_w[2], al, l3_b[0])));
  float v = fmaxf(vp, 0.f) + log1pf(__expf(-fabsf(vp)));  // stable softplus (R2-exact)
  v = fminf(v, 3.f);
  float Tt = distance[e] / (v + 1e-5f);                    // IEEE div (R2-exact)
  float Ti = fminf(fmaxf(rintf(Tt * 0.1f), 0.f), (float)(TT - 1));
  int n = TT - (int)Ti;  // 1..12
  float acl = fminf(fmaxf(al, 0.f), 1.f);
  float F = 1.f / (1.f + acl * Tt);                        // IEEE div (R2-exact)
  float omF = 1.f - F;

  // diffusion-weighted feature[src] sum: F * sum_{k<n} (1-F)^(n-1-k) f[k]
  float row[TT];
  load_row12(feature + ((size_t)se * NB + b) * TT, row);
  float pw = 1.f, s = 0.f;
#pragma unroll
  for (int k = TT - 1; k >= 0; --k) {
    if (k <= n - 1) { s = fmaf(pw, row[k], s); pw *= omF; }
  }
  s *= F;

  // attention logit from node aggregates (collapsed LN+dot)
  float4 As = nodeAgg[(size_t)se * NB + b];
  float4 Ad = nodeAgg[(size_t)de * NB + b];
  float s1 = As.x + Ad.x + Tt;
  float s2 = As.y + Ad.y + Tt * Tt;
  float sd = As.z + Ad.w + consts[2] * Tt;

  float m = s1 * (1.f / 129.f);
  float var = s2 * (1.f / 129.f) - m * m;
  float inv = rsqrtf(var + 1e-5f);
  float a = fmaf(inv, sd - m * consts[0], consts[1]);
  a = (a >= 0.f) ? a : 0.01f * a;  // leaky_relu 0.01

  // no segment-max needed: |a| <= |wg|_2*sqrt(129) << 88 (no exp overflow)
  float ex = __expf(a);
  prod[t] = ex * s;
  atomicAdd(&den[(size_t)se * NB + b], ex);
}

// ---------------- scatter: pred[dst] += prod / den[src] ----------------
__global__ __launch_bounds__(256) void k_edge2(const int* __restrict__ src,
                                               const int* __restrict__ dst,
                                               const float* __restrict__ prod,
                                               const float* __restrict__ den,
                                               float* __restrict__ pred) {
  int t = blockIdx.x * 256 + threadIdx.x;
  int e = t >> 3, b = t & 7;
  float p = prod[t] / den[(size_t)src[e] * NB + b];        // IEEE div (R2-exact)
  atomicAdd(&pred[(size_t)dst[e] * NB + b], p);
}

extern "C" void kernel_launch(void* const* d_in, const int* in_sizes, int n_in,
                              void* d_out, int out_size, void* d_ws, size_t ws_size,
                              hipStream_t stream) {
  const float* feature   = (const float*)d_in[0];
  const float* upstream  = (const float*)d_in[1];
  const float* downstream= (const float*)d_in[2];
  const float* distance  = (const float*)d_in[3];
  const int*   src       = (const int*)d_in[4];
  const int*   dst       = (const int*)d_in[5];
  const float* alpha     = (const float*)d_in[6];
  const float* fc_w      = (const float*)d_in[7];
  const float* ln2_g     = (const float*)d_in[8];
  const float* ln2_b     = (const float*)d_in[9];
  const float* attn_w    = (const float*)d_in[10];
  const float* l11_w     = (const float*)d_in[11];
  const float* l11_b     = (const float*)d_in[12];
  const float* ln11_g    = (const float*)d_in[13];
  const float* ln11_b    = (const float*)d_in[14];
  const float* l12_w     = (const float*)d_in[15];
  const float* l12_b     = (const float*)d_in[16];
  const float* l21_w     = (const float*)d_in[17];
  const float* l21_b     = (const float*)d_in[18];
  const float* ln21_g    = (const float*)d_in[19];
  const float* ln21_b    = (const float*)d_in[20];
  const float* l22_w     = (const float*)d_in[21];
  const float* l22_b     = (const float*)d_in[22];
  const float* l3_w      = (const float*)d_in[23];
  const float* l3_b      = (const float*)d_in[24];
  float* pred = (float*)d_out;

  float* ws = (float*)d_ws;
  float4* nodeAgg = (float4*)ws;                                  // NN*NB float4
  float* prod   = ws + (size_t)NN * NB * 4;                       // NE*NB
  float* den    = prod + (size_t)NE * NB;                         // NN*NB
  float* consts = den + (size_t)NN * NB;                          // 4

  k_init<<<1024, 256, 0, stream>>>((float4*)ws, (float4*)pred);
  k_node<<<(NN * NB + 255) / 256, 256, 0, stream>>>(feature, fc_w, attn_w, ln2_g, ln2_b,
                                                    nodeAgg, consts);

  int eb = NE * NB;
  k_edge1<<<eb / 256, 256, 0, stream>>>(upstream, downstream, distance, alpha, src, dst,
                                        feature, nodeAgg,
                                        l11_w, l11_b, ln11_g, ln11_b, l12_w, l12_b,
                                        l21_w, l21_b, ln21_g, ln21_b, l22_w, l22_b,
                                        l3_w, l3_b, consts, prod, den);
  k_edge2<<<eb / 256, 256, 0, stream>>>(src, dst, prod, den, pred);
}